// Round 1
// baseline (330.816 us; speedup 1.0000x reference)
//
#include <hip/hip_runtime.h>

// LR Coulomb: per-atom neighbor sum of q_i*q_j/d * (1 - fc(d)), segment-summed
// into per-molecule bins. fc is the smooth exponential cutoff at RC=4.6.

#define FACTOR 7.199822675975445f
#define RC     4.6f

__global__ void zero_out_kernel(float* __restrict__ out, int n) {
    int i = blockIdx.x * blockDim.x + threadIdx.x;
    if (i < n) out[i] = 0.0f;
}

__global__ __launch_bounds__(256) void coulomb_kernel(
    const float* __restrict__ coord,    // (N+1)*3
    const float* __restrict__ charges,  // (N+1)
    const int*   __restrict__ nbmat,    // N*M, row-major
    const int*   __restrict__ mol_idx,  // N (sorted)
    float*       __restrict__ out,      // N_MOL
    int N, int Mhalf)                   // Mhalf = M/2
{
    const int wave = threadIdx.x >> 6;
    const int lane = threadIdx.x & 63;
    const int i = blockIdx.x * 4 + wave;
    if (i >= N) return;

    const float xi = coord[3 * i + 0];
    const float yi = coord[3 * i + 1];
    const float zi = coord[3 * i + 2];
    const float qi = charges[i];

    // Each wave owns one nbmat row (M=128 ints = 512B); lane reads 8B -> fully
    // coalesced. Each lane handles neighbors 2*lane and 2*lane+1.
    const int2 jj = reinterpret_cast<const int2*>(nbmat)[(size_t)i * Mhalf + lane];

    float sum = 0.0f;
    #pragma unroll
    for (int k = 0; k < 2; ++k) {
        const int j = (k == 0) ? jj.x : jj.y;
        const bool valid = (j != N) && (j != i);

        // coord[N] / charges[N] are the padding atom -> always a legal address.
        const float xj = coord[3 * j + 0];
        const float yj = coord[3 * j + 1];
        const float zj = coord[3 * j + 2];
        const float qj = charges[j];

        const float dx = xi - xj, dy = yi - yj, dz = zi - zj;
        const float d = sqrtf(dx * dx + dy * dy + dz * dz);
        const float dsafe = valid ? d : 1.0f;

        // exp_cutoff(dsafe, RC)
        const float x = dsafe / RC;
        float inner = 1.0f - x * x;
        inner = fmaxf(inner, 1e-12f);
        const float fc = (dsafe < RC) ? expf(1.0f - 1.0f / inner) : 0.0f;

        const float term = valid ? (qi * qj / dsafe) * (1.0f - fc) : 0.0f;
        sum += term;
    }

    // Wave-wide reduction (64 lanes).
    #pragma unroll
    for (int off = 32; off > 0; off >>= 1)
        sum += __shfl_down(sum, off, 64);

    if (lane == 0) {
        atomicAdd(&out[mol_idx[i]], FACTOR * sum);
    }
}

extern "C" void kernel_launch(void* const* d_in, const int* in_sizes, int n_in,
                              void* d_out, int out_size, void* d_ws, size_t ws_size,
                              hipStream_t stream) {
    const float* coord   = (const float*)d_in[0];
    const float* charges = (const float*)d_in[1];
    const int*   nbmat   = (const int*)d_in[2];
    const int*   mol_idx = (const int*)d_in[3];
    float* out = (float*)d_out;

    const int N = in_sizes[3];              // 200000
    const int M = in_sizes[2] / N;          // 128
    const int Mhalf = M / 2;

    // Zero output bins (harness poisons once; we own initialization).
    zero_out_kernel<<<(out_size + 255) / 256, 256, 0, stream>>>(out, out_size);

    // One wave per atom, 4 waves per block.
    const int blocks = (N + 3) / 4;
    coulomb_kernel<<<blocks, 256, 0, stream>>>(coord, charges, nbmat, mol_idx,
                                               out, N, Mhalf);
}

// Round 2
// 240.206 us; speedup vs baseline: 1.3772x; 1.3772x over previous
//
#include <hip/hip_runtime.h>

// LR Coulomb: per-atom neighbor sum of q_i*q_j/d * (1 - fc(d)), segment-summed
// into per-molecule bins. fc is the smooth exponential cutoff at RC=4.6.
//
// Strategy: pack (x,y,z,q) into float4 in d_ws so each neighbor gather is ONE
// global_load_dwordx4 (divergent gathers dominate; 4 dword gathers -> 1 x4).
// Cutoff depends only on d^2, so no sqrt: rsqrtf(d2) gives 1/d directly.

#define FACTOR 7.199822675975445f
#define RC2    (4.6f * 4.6f)

__global__ void zero_out_kernel(float* __restrict__ out, int n) {
    int i = blockIdx.x * blockDim.x + threadIdx.x;
    if (i < n) out[i] = 0.0f;
}

__global__ void pack_kernel(const float* __restrict__ coord,
                            const float* __restrict__ charges,
                            float4* __restrict__ xyzq, int n1) {
    int i = blockIdx.x * blockDim.x + threadIdx.x;
    if (i < n1) {
        xyzq[i] = make_float4(coord[3 * i + 0], coord[3 * i + 1],
                              coord[3 * i + 2], charges[i]);
    }
}

__global__ __launch_bounds__(256) void coulomb_kernel(
    const float4* __restrict__ xyzq,    // (N+1), packed x,y,z,q
    const int*    __restrict__ nbmat,   // N*M, row-major
    const int*    __restrict__ mol_idx, // N (sorted)
    float*        __restrict__ out,     // N_MOL
    int N, int Mhalf)                   // Mhalf = M/2
{
    const int wave = threadIdx.x >> 6;
    const int lane = threadIdx.x & 63;
    const int i = blockIdx.x * 4 + wave;
    if (i >= N) return;

    const float4 me = xyzq[i];
    const float xi = me.x, yi = me.y, zi = me.z, qi = me.w;

    // One nbmat row per wave (M=128 ints = 512B); lane reads 8B, coalesced.
    // Non-temporal: nbmat is streamed once, keep xyzq hot in L2.
    const long long packed = __builtin_nontemporal_load(
        reinterpret_cast<const long long*>(nbmat) + (size_t)i * Mhalf + lane);
    const int j0 = (int)(packed & 0xffffffffLL);
    const int j1 = (int)(packed >> 32);

    float sum = 0.0f;
    #pragma unroll
    for (int k = 0; k < 2; ++k) {
        const int j = (k == 0) ? j0 : j1;
        const bool valid = (j != N) && (j != i);

        const float4 nb = xyzq[j];  // single dwordx4 gather
        const float dx = xi - nb.x, dy = yi - nb.y, dz = zi - nb.z;
        const float d2 = dx * dx + dy * dy + dz * dz;

        // fc depends only on d^2: inner = 1 - d2/RC^2
        float inner = fmaxf(1.0f - d2 * (1.0f / RC2), 1e-12f);
        const float fc = (d2 < RC2) ? expf(1.0f - 1.0f / inner) : 0.0f;

        const float rinv = rsqrtf(d2);          // 1/d
        const float term = (qi * nb.w) * rinv * (1.0f - fc);
        sum += valid ? term : 0.0f;
    }

    // Wave-wide reduction (64 lanes).
    #pragma unroll
    for (int off = 32; off > 0; off >>= 1)
        sum += __shfl_down(sum, off, 64);

    if (lane == 0) {
        atomicAdd(&out[mol_idx[i]], FACTOR * sum);
    }
}

// Fallback (no packing) in case ws_size is too small for the xyzq table.
__global__ __launch_bounds__(256) void coulomb_kernel_unpacked(
    const float* __restrict__ coord,
    const float* __restrict__ charges,
    const int*   __restrict__ nbmat,
    const int*   __restrict__ mol_idx,
    float*       __restrict__ out,
    int N, int Mhalf)
{
    const int wave = threadIdx.x >> 6;
    const int lane = threadIdx.x & 63;
    const int i = blockIdx.x * 4 + wave;
    if (i >= N) return;

    const float xi = coord[3 * i + 0];
    const float yi = coord[3 * i + 1];
    const float zi = coord[3 * i + 2];
    const float qi = charges[i];

    const long long packed = __builtin_nontemporal_load(
        reinterpret_cast<const long long*>(nbmat) + (size_t)i * Mhalf + lane);
    const int j0 = (int)(packed & 0xffffffffLL);
    const int j1 = (int)(packed >> 32);

    float sum = 0.0f;
    #pragma unroll
    for (int k = 0; k < 2; ++k) {
        const int j = (k == 0) ? j0 : j1;
        const bool valid = (j != N) && (j != i);
        const float dx = xi - coord[3 * j + 0];
        const float dy = yi - coord[3 * j + 1];
        const float dz = zi - coord[3 * j + 2];
        const float d2 = dx * dx + dy * dy + dz * dz;
        float inner = fmaxf(1.0f - d2 * (1.0f / RC2), 1e-12f);
        const float fc = (d2 < RC2) ? expf(1.0f - 1.0f / inner) : 0.0f;
        const float rinv = rsqrtf(d2);
        const float term = (qi * charges[j]) * rinv * (1.0f - fc);
        sum += valid ? term : 0.0f;
    }

    #pragma unroll
    for (int off = 32; off > 0; off >>= 1)
        sum += __shfl_down(sum, off, 64);

    if (lane == 0) {
        atomicAdd(&out[mol_idx[i]], FACTOR * sum);
    }
}

extern "C" void kernel_launch(void* const* d_in, const int* in_sizes, int n_in,
                              void* d_out, int out_size, void* d_ws, size_t ws_size,
                              hipStream_t stream) {
    const float* coord   = (const float*)d_in[0];
    const float* charges = (const float*)d_in[1];
    const int*   nbmat   = (const int*)d_in[2];
    const int*   mol_idx = (const int*)d_in[3];
    float* out = (float*)d_out;

    const int N  = in_sizes[3];         // 200000
    const int n1 = in_sizes[1];         // N+1 (includes padding atom)
    const int M  = in_sizes[2] / N;     // 128
    const int Mhalf = M / 2;

    zero_out_kernel<<<(out_size + 255) / 256, 256, 0, stream>>>(out, out_size);

    const int blocks = (N + 3) / 4;     // one wave per atom, 4 waves/block

    if (ws_size >= (size_t)n1 * sizeof(float4)) {
        float4* xyzq = (float4*)d_ws;
        pack_kernel<<<(n1 + 255) / 256, 256, 0, stream>>>(coord, charges, xyzq, n1);
        coulomb_kernel<<<blocks, 256, 0, stream>>>(xyzq, nbmat, mol_idx,
                                                   out, N, Mhalf);
    } else {
        coulomb_kernel_unpacked<<<blocks, 256, 0, stream>>>(coord, charges, nbmat,
                                                            mol_idx, out, N, Mhalf);
    }
}

// Round 3
// 142.887 us; speedup vs baseline: 2.3152x; 1.6811x over previous
//
#include <hip/hip_runtime.h>

// LR Coulomb: per-atom neighbor sum of q_i*q_j/d * (1 - fc(d)), segment-summed
// into per-molecule bins. fc is the smooth exponential cutoff at RC=4.6.
//
// R2 analysis: latency-bound (HBM 3.5%, VALU 18%). Each wave had only 3 loads
// in flight. This version: 4 atoms per wave -> 4 nbmat loads + 8 float4
// gathers + 4 center loads issued before compute (4x MLP), reductions and
// atomics amortized (atomics merged when atoms share a molecule bin).

#define FACTOR 7.199822675975445f
#define RC2    (4.6f * 4.6f)
#define ATOMS  4

__global__ void zero_out_kernel(float* __restrict__ out, int n) {
    int i = blockIdx.x * blockDim.x + threadIdx.x;
    if (i < n) out[i] = 0.0f;
}

__global__ void pack_kernel(const float* __restrict__ coord,
                            const float* __restrict__ charges,
                            float4* __restrict__ xyzq, int n1) {
    int i = blockIdx.x * blockDim.x + threadIdx.x;
    if (i < n1) {
        xyzq[i] = make_float4(coord[3 * i + 0], coord[3 * i + 1],
                              coord[3 * i + 2], charges[i]);
    }
}

__global__ __launch_bounds__(256) void coulomb_kernel(
    const float4* __restrict__ xyzq,    // (N+1), packed x,y,z,q
    const int*    __restrict__ nbmat,   // N*M, row-major
    const int*    __restrict__ mol_idx, // N (sorted)
    float*        __restrict__ out,     // N_MOL
    int N, int Mhalf)                   // Mhalf = M/2
{
    const int wave = threadIdx.x >> 6;
    const int lane = threadIdx.x & 63;
    const long long base = ((long long)blockIdx.x * 4 + wave) * ATOMS;
    if (base >= N) return;

    // --- Issue ALL loads before any compute (maximize MLP) ---

    // 4 neighbor-row loads (8B/lane, coalesced, streamed once -> nontemporal).
    int j[ATOMS][2];
    #pragma unroll
    for (int a = 0; a < ATOMS; ++a) {
        const long long row = (base + a < N) ? (base + a) : (N - 1);
        const long long packed = __builtin_nontemporal_load(
            reinterpret_cast<const long long*>(nbmat) + row * Mhalf + lane);
        j[a][0] = (int)(packed & 0xffffffffLL);
        j[a][1] = (int)(packed >> 32);
    }

    // 8 divergent float4 gathers (table is 3.2MB -> L2-resident per XCD).
    float4 nb[ATOMS][2];
    #pragma unroll
    for (int a = 0; a < ATOMS; ++a) {
        nb[a][0] = xyzq[j[a][0]];
        nb[a][1] = xyzq[j[a][1]];
    }

    // 4 center loads (wave-uniform address -> broadcast, cheap).
    float4 me[ATOMS];
    #pragma unroll
    for (int a = 0; a < ATOMS; ++a) {
        me[a] = xyzq[(base + a < N) ? (base + a) : (N - 1)];
    }

    // --- Compute 8 interactions ---
    float sums[ATOMS];
    #pragma unroll
    for (int a = 0; a < ATOMS; ++a) {
        const int i = (int)((base + a < N) ? (base + a) : (N - 1));
        float s = 0.0f;
        #pragma unroll
        for (int k = 0; k < 2; ++k) {
            const int jj = j[a][k];
            const bool valid = (jj != N) && (jj != i);
            const float dx = me[a].x - nb[a][k].x;
            const float dy = me[a].y - nb[a][k].y;
            const float dz = me[a].z - nb[a][k].z;
            const float d2 = dx * dx + dy * dy + dz * dz;
            float inner = fmaxf(1.0f - d2 * (1.0f / RC2), 1e-12f);
            const float fc = (d2 < RC2) ? __expf(1.0f - 1.0f / inner) : 0.0f;
            const float term = (me[a].w * nb[a][k].w) * rsqrtf(d2) * (1.0f - fc);
            s += valid ? term : 0.0f;
        }
        sums[a] = s;
    }

    // --- Wave-wide butterfly reductions (all lanes end with each sum) ---
    #pragma unroll
    for (int off = 32; off > 0; off >>= 1) {
        #pragma unroll
        for (int a = 0; a < ATOMS; ++a)
            sums[a] += __shfl_xor(sums[a], off, 64);
    }

    // --- Merge atomics by molecule (mol_idx sorted; usually 1 bin/wave) ---
    if (lane == 0) {
        float acc = 0.0f;
        int cur = -1;
        #pragma unroll
        for (int a = 0; a < ATOMS; ++a) {
            if (base + a < N) {
                const int ma = mol_idx[base + a];
                if (ma != cur) {
                    if (cur >= 0) atomicAdd(&out[cur], FACTOR * acc);
                    cur = ma;
                    acc = 0.0f;
                }
                acc += sums[a];
            }
        }
        if (cur >= 0) atomicAdd(&out[cur], FACTOR * acc);
    }
}

// Fallback (no packing) in case ws_size is too small for the xyzq table.
__global__ __launch_bounds__(256) void coulomb_kernel_unpacked(
    const float* __restrict__ coord,
    const float* __restrict__ charges,
    const int*   __restrict__ nbmat,
    const int*   __restrict__ mol_idx,
    float*       __restrict__ out,
    int N, int Mhalf)
{
    const int wave = threadIdx.x >> 6;
    const int lane = threadIdx.x & 63;
    const int i = blockIdx.x * 4 + wave;
    if (i >= N) return;

    const float xi = coord[3 * i + 0];
    const float yi = coord[3 * i + 1];
    const float zi = coord[3 * i + 2];
    const float qi = charges[i];

    const long long packed = __builtin_nontemporal_load(
        reinterpret_cast<const long long*>(nbmat) + (size_t)i * Mhalf + lane);
    const int j0 = (int)(packed & 0xffffffffLL);
    const int j1 = (int)(packed >> 32);

    float sum = 0.0f;
    #pragma unroll
    for (int k = 0; k < 2; ++k) {
        const int j = (k == 0) ? j0 : j1;
        const bool valid = (j != N) && (j != i);
        const float dx = xi - coord[3 * j + 0];
        const float dy = yi - coord[3 * j + 1];
        const float dz = zi - coord[3 * j + 2];
        const float d2 = dx * dx + dy * dy + dz * dz;
        float inner = fmaxf(1.0f - d2 * (1.0f / RC2), 1e-12f);
        const float fc = (d2 < RC2) ? __expf(1.0f - 1.0f / inner) : 0.0f;
        const float term = (qi * charges[j]) * rsqrtf(d2) * (1.0f - fc);
        sum += valid ? term : 0.0f;
    }

    #pragma unroll
    for (int off = 32; off > 0; off >>= 1)
        sum += __shfl_down(sum, off, 64);

    if (lane == 0) {
        atomicAdd(&out[mol_idx[i]], FACTOR * sum);
    }
}

extern "C" void kernel_launch(void* const* d_in, const int* in_sizes, int n_in,
                              void* d_out, int out_size, void* d_ws, size_t ws_size,
                              hipStream_t stream) {
    const float* coord   = (const float*)d_in[0];
    const float* charges = (const float*)d_in[1];
    const int*   nbmat   = (const int*)d_in[2];
    const int*   mol_idx = (const int*)d_in[3];
    float* out = (float*)d_out;

    const int N  = in_sizes[3];         // 200000
    const int n1 = in_sizes[1];         // N+1 (includes padding atom)
    const int M  = in_sizes[2] / N;     // 128
    const int Mhalf = M / 2;

    zero_out_kernel<<<(out_size + 255) / 256, 256, 0, stream>>>(out, out_size);

    if (ws_size >= (size_t)n1 * sizeof(float4)) {
        float4* xyzq = (float4*)d_ws;
        pack_kernel<<<(n1 + 255) / 256, 256, 0, stream>>>(coord, charges, xyzq, n1);
        // 4 atoms per wave, 4 waves per block -> 16 atoms per block.
        const int blocks = (N + 4 * ATOMS - 1) / (4 * ATOMS);
        coulomb_kernel<<<blocks, 256, 0, stream>>>(xyzq, nbmat, mol_idx,
                                                   out, N, Mhalf);
    } else {
        const int blocks = (N + 3) / 4;
        coulomb_kernel_unpacked<<<blocks, 256, 0, stream>>>(coord, charges, nbmat,
                                                            mol_idx, out, N, Mhalf);
    }
}

// Round 5
// 132.671 us; speedup vs baseline: 2.4935x; 1.0770x over previous
//
#include <hip/hip_runtime.h>
#include <hip/hip_fp16.h>

// LR Coulomb: per-atom neighbor sum of q_i*q_j/d * (1 - fc(d)), segment-summed
// into per-molecule bins. fc is the smooth exponential cutoff at RC=4.6.
//
// R3 analysis: still latency-bound (HBM 6%, VALU 28%). Lever: more in-flight
// divergent gathers per wave WITHOUT losing occupancy. Atom records packed to
// half4 (8B) -> gather buffer for 8 atoms/wave fits in ~32 VGPRs. Each wave:
// 4 int4 nbmat loads (2 rows each) + 4 center gathers + 16 neighbor gathers,
// all issued before compute. Per-32-lane-half reduction, merged atomics.
//
// R4 fix: __builtin_nontemporal_load rejects HIP_vector_type -> use clang
// ext_vector_type(4) for the nbmat row loads.

#define FACTOR 7.199822675975445f
#define RC2    (4.6f * 4.6f)
#define ATOMS  8                 // per wave (2 per chunk x 4 chunks)

typedef int v4i __attribute__((ext_vector_type(4)));

__global__ void zero_out_kernel(float* __restrict__ out, int n) {
    int i = blockIdx.x * blockDim.x + threadIdx.x;
    if (i < n) out[i] = 0.0f;
}

// Pack (x,y,z,q) -> 4 x fp16 in 8 bytes.
__global__ void pack_kernel(const float* __restrict__ coord,
                            const float* __restrict__ charges,
                            uint2* __restrict__ tbl, int n1) {
    int i = blockIdx.x * blockDim.x + threadIdx.x;
    if (i < n1) {
        unsigned hx = __half_as_ushort(__float2half_rn(coord[3 * i + 0]));
        unsigned hy = __half_as_ushort(__float2half_rn(coord[3 * i + 1]));
        unsigned hz = __half_as_ushort(__float2half_rn(coord[3 * i + 2]));
        unsigned hq = __half_as_ushort(__float2half_rn(charges[i]));
        tbl[i] = make_uint2(hx | (hy << 16), hz | (hq << 16));
    }
}

__device__ __forceinline__ float4 unpack_h4(uint2 p) {
    __half2 a = *reinterpret_cast<__half2*>(&p.x);
    __half2 b = *reinterpret_cast<__half2*>(&p.y);
    float2 fa = __half22float2(a);
    float2 fb = __half22float2(b);
    return make_float4(fa.x, fa.y, fb.x, fb.y);
}

__global__ __launch_bounds__(256) void coulomb_kernel(
    const uint2* __restrict__ tbl,      // (N+1) packed half4 records
    const int*   __restrict__ nbmat,    // N*M row-major
    const int*   __restrict__ mol_idx,  // N (sorted)
    float*       __restrict__ out,      // N_MOL
    int N8, int N, int M)               // N8 = N rounded down to ATOMS
{
    const int wave = threadIdx.x >> 6;
    const int lane = threadIdx.x & 63;
    const int half = lane >> 5;         // which row of the chunk's 2 rows
    const int base = (blockIdx.x * 4 + wave) * ATOMS;
    if (base >= N8) return;

    // --- centers: 4 chunk x 2 rows; each lane needs atom (base+2c+half) ---
    uint2 mep[4];
    #pragma unroll
    for (int c = 0; c < 4; ++c)
        mep[c] = tbl[base + 2 * c + half];

    // --- nbmat: chunk c covers rows {base+2c, base+2c+1} = 256 ints = 1KB.
    //     lane reads int4 at offset 4*lane (lanes 0-31 -> row0, 32-63 -> row1).
    v4i jv[4];
    #pragma unroll
    for (int c = 0; c < 4; ++c) {
        const v4i* rowp = reinterpret_cast<const v4i*>(
            nbmat + (size_t)(base + 2 * c) * M);
        jv[c] = __builtin_nontemporal_load(rowp + lane);
    }

    // --- 16 divergent 8B gathers, all issued before compute ---
    uint2 nbp[4][4];
    #pragma unroll
    for (int c = 0; c < 4; ++c) {
        nbp[c][0] = tbl[jv[c].x];
        nbp[c][1] = tbl[jv[c].y];
        nbp[c][2] = tbl[jv[c].z];
        nbp[c][3] = tbl[jv[c].w];
    }

    // --- compute ---
    float sums[4];
    #pragma unroll
    for (int c = 0; c < 4; ++c) {
        const int i = base + 2 * c + half;
        const float4 me = unpack_h4(mep[c]);
        float s = 0.0f;
        const int jj[4] = {jv[c].x, jv[c].y, jv[c].z, jv[c].w};
        #pragma unroll
        for (int k = 0; k < 4; ++k) {
            const int j = jj[k];
            const bool valid = (j != N) && (j != i);
            const float4 nb = unpack_h4(nbp[c][k]);
            const float dx = me.x - nb.x;
            const float dy = me.y - nb.y;
            const float dz = me.z - nb.z;
            const float d2 = dx * dx + dy * dy + dz * dz;
            float inner = fmaxf(1.0f - d2 * (1.0f / RC2), 1e-12f);
            const float fc = (d2 < RC2) ? __expf(1.0f - 1.0f / inner) : 0.0f;
            const float term = (me.w * nb.w) * rsqrtf(d2) * (1.0f - fc);
            s += valid ? term : 0.0f;
        }
        sums[c] = s;
    }

    // --- reduce within each 32-lane half (xor offsets stay inside half) ---
    #pragma unroll
    for (int off = 16; off > 0; off >>= 1) {
        #pragma unroll
        for (int c = 0; c < 4; ++c)
            sums[c] += __shfl_xor(sums[c], off, 64);
    }

    // --- lanes 0 and 32 own atoms {base+2c+half}; merge same-molecule bins ---
    if ((lane & 31) == 0) {
        float acc = 0.0f;
        int cur = -1;
        #pragma unroll
        for (int c = 0; c < 4; ++c) {
            const int ia = base + 2 * c + half;
            const int ma = mol_idx[ia];
            if (ma != cur) {
                if (cur >= 0) atomicAdd(&out[cur], FACTOR * acc);
                cur = ma;
                acc = 0.0f;
            }
            acc += sums[c];
        }
        if (cur >= 0) atomicAdd(&out[cur], FACTOR * acc);
    }
}

// Tail: one wave per atom for the N%ATOMS remainder (never used at N=200000).
__global__ __launch_bounds__(256) void coulomb_tail_kernel(
    const uint2* __restrict__ tbl,
    const int*   __restrict__ nbmat,
    const int*   __restrict__ mol_idx,
    float*       __restrict__ out,
    int start, int N, int Mhalf)
{
    const int wave = threadIdx.x >> 6;
    const int lane = threadIdx.x & 63;
    const int i = start + blockIdx.x * 4 + wave;
    if (i >= N) return;

    const float4 me = unpack_h4(tbl[i]);
    const long long packed = __builtin_nontemporal_load(
        reinterpret_cast<const long long*>(nbmat) + (size_t)i * Mhalf + lane);
    const int j0 = (int)(packed & 0xffffffffLL);
    const int j1 = (int)(packed >> 32);

    float sum = 0.0f;
    #pragma unroll
    for (int k = 0; k < 2; ++k) {
        const int j = (k == 0) ? j0 : j1;
        const bool valid = (j != N) && (j != i);
        const float4 nb = unpack_h4(tbl[j]);
        const float dx = me.x - nb.x, dy = me.y - nb.y, dz = me.z - nb.z;
        const float d2 = dx * dx + dy * dy + dz * dz;
        float inner = fmaxf(1.0f - d2 * (1.0f / RC2), 1e-12f);
        const float fc = (d2 < RC2) ? __expf(1.0f - 1.0f / inner) : 0.0f;
        const float term = (me.w * nb.w) * rsqrtf(d2) * (1.0f - fc);
        sum += valid ? term : 0.0f;
    }
    #pragma unroll
    for (int off = 32; off > 0; off >>= 1)
        sum += __shfl_down(sum, off, 64);
    if (lane == 0) atomicAdd(&out[mol_idx[i]], FACTOR * sum);
}

extern "C" void kernel_launch(void* const* d_in, const int* in_sizes, int n_in,
                              void* d_out, int out_size, void* d_ws, size_t ws_size,
                              hipStream_t stream) {
    const float* coord   = (const float*)d_in[0];
    const float* charges = (const float*)d_in[1];
    const int*   nbmat   = (const int*)d_in[2];
    const int*   mol_idx = (const int*)d_in[3];
    float* out = (float*)d_out;

    const int N  = in_sizes[3];         // 200000
    const int n1 = in_sizes[1];         // N+1
    const int M  = in_sizes[2] / N;     // 128

    zero_out_kernel<<<(out_size + 255) / 256, 256, 0, stream>>>(out, out_size);

    uint2* tbl = (uint2*)d_ws;          // n1 * 8 bytes, fits easily
    pack_kernel<<<(n1 + 255) / 256, 256, 0, stream>>>(coord, charges, tbl, n1);

    const int N8 = N - (N % ATOMS);
    // 8 atoms/wave, 4 waves/block -> 32 atoms/block.
    const int blocks = (N8 + 4 * ATOMS - 1) / (4 * ATOMS);
    coulomb_kernel<<<blocks, 256, 0, stream>>>(tbl, nbmat, mol_idx, out,
                                               N8, N, M);
    const int rem = N - N8;
    if (rem > 0) {
        coulomb_tail_kernel<<<(rem + 3) / 4, 256, 0, stream>>>(
            tbl, nbmat, mol_idx, out, N8, N, M / 2);
    }
}